// Round 7
// baseline (557.481 us; speedup 1.0000x reference)
//
#include <hip/hip_runtime.h>

using f32x4  = __attribute__((ext_vector_type(4))) float;
using short8 = __attribute__((ext_vector_type(8))) short;
using short4v= __attribute__((ext_vector_type(4))) short;
typedef __attribute__((ext_vector_type(8))) __bf16 bf16x8;

__device__ static inline short f2bf(float f){
    unsigned u = __builtin_bit_cast(unsigned, f);
    u += 0x7fffu + ((u >> 16) & 1u);      // RNE
    return (short)(u >> 16);
}

__device__ static inline void gload_lds16(const void* g, void* l){
    __builtin_amdgcn_global_load_lds(
        (const __attribute__((address_space(1))) void*)g,
        (__attribute__((address_space(3))) void*)l, 16, 0, 0);
}

// ---------------- GEMM: C[M,N] = A[M,K] @ B[N,K]^T  (bf16 in, f32 acc) ----
// 128x128 tile, BK=64, 4 waves of 64x64 — proven m97-style kernel, used for
// the small/medium stages. (Stage 6 uses gemm_bt256 below.)
#define BKK 64

template<int EPI, bool T2D>
__global__ __launch_bounds__(256, 2)
void gemm_bt(const short* __restrict__ A, const short* __restrict__ B,
             float* __restrict__ outF, short* __restrict__ outB,
             const float* __restrict__ bias,
             const float* __restrict__ addmat, const float* __restrict__ mask,
             int K, int ldc, int Ncheck,
             long sA, long sB, long sC, long sX, int maskStride)
{
    __shared__ short Abuf[128*BKK];
    __shared__ short Bbuf[128*BKK];
    const int tid  = threadIdx.x;
    const int wave = tid >> 6;
    const int lane = tid & 63;
    const int bz   = blockIdx.z;

    int bx = blockIdx.x, by = blockIdx.y;
    if constexpr (T2D) {
        const int GX = gridDim.x, GY = gridDim.y;
        const int f  = blockIdx.y * GX + blockIdx.x;
        const int nfull  = GX >> 3;
        const int fullsz = (nfull << 3) * GY;
        int mg, mloc, nloc, nbase;
        if (f < fullsz) {
            const int band = f / (GY << 3);
            const int r    = f - band * (GY << 3);
            mg   = r >> 6;
            const int rr = r & 63;
            mloc = rr & 7; nloc = rr >> 3;
            nbase = band << 3;
        } else {
            const int rem = GX & 7;
            const int fp  = f - fullsz;
            const int gsz = rem << 3;
            mg   = fp / gsz;
            const int rr = fp - mg * gsz;
            mloc = rr & 7; nloc = rr >> 3;
            nbase = nfull << 3;
        }
        bx = nbase + nloc;
        by = (mg << 3) + mloc;
    }
    const int m0 = by * 128;
    const int n0 = bx * 128;
    const short* Ab = A + (long)bz * sA;
    const short* Bb = B + (long)bz * sB;

    const int wr = (wave >> 1) * 64;
    const int wc = (wave &  1) * 64;

    f32x4 acc[4][4];
    #pragma unroll
    for (int i=0;i<4;++i)
        #pragma unroll
        for (int j=0;j<4;++j) acc[i][j] = (f32x4){0.f,0.f,0.f,0.f};

    const int srow = wave*32 + (lane >> 3);
    const int kch  = (lane & 7) ^ (lane >> 3);
    const short* gA = Ab + (long)(m0 + srow)*K + kch*8;
    const short* gB = Bb + (long)(n0 + srow)*K + kch*8;
    short* lA = Abuf + wave*32*BKK;
    short* lB = Bbuf + wave*32*BKK;

    for (int k0 = 0; k0 < K; k0 += BKK) {
        __syncthreads();
        #pragma unroll
        for (int is=0; is<4; ++is){
            gload_lds16(gA + k0 + (long)is*8*K, lA + is*8*BKK);
            gload_lds16(gB + k0 + (long)is*8*K, lB + is*8*BKK);
        }
        __syncthreads();
        #pragma unroll
        for (int ks=0; ks<2; ++ks){
            bf16x8 af[4], bfr[4];
            const int chunk = ks*4 + (lane >> 4);
            #pragma unroll
            for (int mi=0;mi<4;++mi){
                int row = wr + mi*16 + (lane & 15);
                af[mi] = *(const bf16x8*)((const char*)Abuf + row*128 + ((chunk ^ (row & 7))<<4));
            }
            #pragma unroll
            for (int ni=0;ni<4;++ni){
                int row = wc + ni*16 + (lane & 15);
                bfr[ni] = *(const bf16x8*)((const char*)Bbuf + row*128 + ((chunk ^ (row & 7))<<4));
            }
            #pragma unroll
            for (int mi=0;mi<4;++mi)
                #pragma unroll
                for (int ni=0;ni<4;++ni)
                    acc[mi][ni] = __builtin_amdgcn_mfma_f32_16x16x32_bf16(af[mi], bfr[ni], acc[mi][ni], 0, 0, 0);
        }
    }

    const int rb = (lane >> 4) * 4;
    const int cb = lane & 15;
    #pragma unroll
    for (int mi=0;mi<4;++mi){
        #pragma unroll
        for (int r=0;r<4;++r){
            const int row = m0 + wr + mi*16 + rb + r;
            #pragma unroll
            for (int ni=0;ni<4;++ni){
                const int col = n0 + wc + ni*16 + cb;
                float v = acc[mi][ni][r];
                if constexpr (EPI == 0) {
                    v += addmat[(long)bz*sX + (long)row*ldc + col]
                         - 10000.f * mask[bz*maskStride + col];
                    outF[(long)bz*sC + (long)row*ldc + col] = v;
                } else if constexpr (EPI == 1) {
                    outB[(long)bz*sC + (long)row*ldc + col] = f2bf(v);
                } else if constexpr (EPI == 3) {
                    if (col < Ncheck) outF[(long)row*ldc + col] = v + bias[col];
                } else if constexpr (EPI == 4) {
                    outB[(long)row*ldc + col] = f2bf(v + bias[col]);
                }
            }
        }
    }
}

// ------------- stage-6 GEMM: 256x256 tile, 8 waves, BK=32, dbuf+vmcnt ------
// Per-wave output 128x64 (8 M-frags x 4 N-frags): 32 MFMA per 12 ds_read_b128
// = 42.7 FLOP/LDS-byte (2.7x the 128^2 kernel) -> matrix pipe feedable.
// LDS 64 KB total (2 bufs x (A 16KB + B 16KB)), 1 block x 8 waves / CU.
// R5-proven sync skeleton: barrier / issue next-tile loads / counted
// vmcnt(4) (never drains in main loop) / barrier / compute.
// LDS swizzle (4 chunks of 16B per 64B row): slot = chunk ^ ((row>>1)&3);
// pre-swizzled global source (rule #21), 2-way bank aliasing = free (m136).
template<bool T2D>
__global__ __launch_bounds__(512, 2)
void gemm_bt256(const short* __restrict__ A, const short* __restrict__ B,
                float* __restrict__ outF, const float* __restrict__ bias,
                int K, int ldc, int Ncheck, int maxBrow)
{
    __shared__ __align__(16) short Abuf[2][256*32];
    __shared__ __align__(16) short Bbuf[2][256*32];
    const int tid  = threadIdx.x;
    const int wave = tid >> 6;
    const int lane = tid & 63;

    int bx = blockIdx.x, by = blockIdx.y;
    if constexpr (T2D) {   // 8x8 super-tiles; requires GX%8==0 && GY%8==0
        const int GX = gridDim.x, GY = gridDim.y;
        const int f  = blockIdx.y * GX + blockIdx.x;
        const int band = f / (GY << 3);
        const int r2   = f - band * (GY << 3);
        const int mg   = r2 >> 6;
        const int rr   = r2 & 63;
        bx = (band << 3) + (rr >> 3);
        by = (mg << 3) + (rr & 7);
    }
    const int m0 = by * 256;
    const int n0 = bx * 256;

    const int wr = (wave >> 2) * 128;   // 2 wave-rows of M
    const int wc = (wave & 3) * 64;     // 4 wave-cols of N

    f32x4 acc[8][4];
    #pragma unroll
    for (int i=0;i<8;++i)
        #pragma unroll
        for (int j=0;j<4;++j) acc[i][j] = (f32x4){0.f,0.f,0.f,0.f};

    // staging: per issue, 512 threads cover 128 rows x 4 chunks of 16B
    const int srow = wave*16 + (lane >> 2);              // [0,128)
    const int kch  = (lane & 3) ^ ((lane >> 3) & 3);     // pre-swizzled chunk
    const short* gA0 = A + (long)(m0 + srow)       * K + kch*8;
    const short* gA1 = A + (long)(m0 + 128 + srow) * K + kch*8;
    int br0 = n0 + srow;        if (br0 > maxBrow) br0 = maxBrow;
    int br1 = n0 + 128 + srow;  if (br1 > maxBrow) br1 = maxBrow;
    const short* gB0 = B + (long)br0 * K + kch*8;
    const short* gB1 = B + (long)br1 * K + kch*8;
    const int lofs = wave*16*32;                          // wave-uniform base

    const int nt = K / 32;

    auto STAGE = [&](int buf, int t){
        const long k0 = (long)t * 32;
        gload_lds16(gA0 + k0, &Abuf[buf][lofs]);
        gload_lds16(gA1 + k0, &Abuf[buf][128*32 + lofs]);
        gload_lds16(gB0 + k0, &Bbuf[buf][lofs]);
        gload_lds16(gB1 + k0, &Bbuf[buf][128*32 + lofs]);
    };

    STAGE(0, 0);   // prologue: tile 0 -> buf 0

    const int qsl = (((lane >> 4) ^ ((lane >> 1) & 3)) << 4); // byte slot in row
    const int rA  = wr + (lane & 15);
    const int rB  = wc + (lane & 15);

    for (int t = 0; t < nt; ++t) {
        const int cur = t & 1, nxt = cur ^ 1;
        // all waves finished reading buf[nxt] in iter t-1
        __builtin_amdgcn_s_barrier();
        if (t + 1 < nt) {
            STAGE(nxt, t + 1);
            asm volatile("s_waitcnt vmcnt(4)" ::: "memory");  // tile-t landed
        } else {
            asm volatile("s_waitcnt vmcnt(0)" ::: "memory");
        }
        __builtin_amdgcn_s_barrier();   // collectively: tile t fully in LDS
        asm volatile("" ::: "memory");

        bf16x8 af[8], bfr[4];
        #pragma unroll
        for (int ni=0;ni<4;++ni)
            bfr[ni] = *(const bf16x8*)((const char*)&Bbuf[cur][0] + (rB + ni*16)*64 + qsl);
        #pragma unroll
        for (int mi=0;mi<8;++mi)
            af[mi]  = *(const bf16x8*)((const char*)&Abuf[cur][0] + (rA + mi*16)*64 + qsl);
        #pragma unroll
        for (int mi=0;mi<8;++mi)
            #pragma unroll
            for (int ni=0;ni<4;++ni)
                acc[mi][ni] = __builtin_amdgcn_mfma_f32_16x16x32_bf16(af[mi], bfr[ni], acc[mi][ni], 0, 0, 0);
    }

    // epilogue: C/D layout col=lane&15, row=(lane>>4)*4+reg
    const int rb = (lane >> 4) * 4;
    const int cb = lane & 15;
    #pragma unroll
    for (int mi=0;mi<8;++mi){
        #pragma unroll
        for (int r=0;r<4;++r){
            const long row = (long)m0 + wr + mi*16 + rb + r;
            #pragma unroll
            for (int ni=0;ni<4;++ni){
                const int col = n0 + wc + ni*16 + cb;
                if (col < Ncheck)
                    outF[row*ldc + col] = acc[mi][ni][r] + bias[col];
            }
        }
    }
}

// ---------------- f32 -> bf16 (vector, zero-pad tail [n, ntot)) -----------
__global__ __launch_bounds__(256)
void conv_bf16(const float* __restrict__ in, short* __restrict__ out, long n, long ntot)
{
    const long stride = (long)gridDim.x * 2048;
    for (long i = ((long)blockIdx.x*256 + threadIdx.x)*8; i < ntot; i += stride){
        short8 o = (short8){0,0,0,0,0,0,0,0};
        if (i < n){
            f32x4 a = *(const f32x4*)(in + i);
            f32x4 b = *(const f32x4*)(in + i + 4);
            o[0]=f2bf(a[0]); o[1]=f2bf(a[1]); o[2]=f2bf(a[2]); o[3]=f2bf(a[3]);
            o[4]=f2bf(b[0]); o[5]=f2bf(b[1]); o[6]=f2bf(b[2]); o[7]=f2bf(b[3]);
        }
        *(short8*)(out + i) = o;
    }
}

// ---------------- f32 [R,Cin] -> bf16 [R,Cpad], zero cols >= Cin ----------
__global__ __launch_bounds__(256)
void conv_pad(const float* __restrict__ in, short* __restrict__ out,
              int Cin, int Cpad, int total)
{
    int idx = blockIdx.x*256 + threadIdx.x;
    if (idx >= total) return;
    int r = idx / Cpad, c = idx - r*Cpad;
    short v = 0;
    if (c < Cin) v = f2bf(in[(long)r*Cin + c]);
    out[idx] = v;
}

// ---------------- per-batch transpose f32 [R,C] -> bf16 [C,R] -------------
__global__ __launch_bounds__(256)
void transpose_to_bf16(const float* __restrict__ in, short* __restrict__ out, int R, int C)
{
    __shared__ float t[32][33];
    const long boff = (long)blockIdx.z * R * C;
    const float* inb = in + boff;
    short* outb = out + boff;
    int c0 = blockIdx.x*32, r0 = blockIdx.y*32;
    int tx = threadIdx.x & 31, ty = threadIdx.x >> 5;   // 32 x 8
    #pragma unroll
    for (int j=0;j<32;j+=8) t[ty+j][tx] = inb[(long)(r0+ty+j)*C + c0+tx];
    __syncthreads();
    #pragma unroll
    for (int j=0;j<32;j+=8) outb[(long)(c0+ty+j)*R + r0+tx] = f2bf(t[tx][ty+j]);
}

// ---------------- wave-per-row softmax, f32 [.,512] -> bf16 ---------------
__global__ __launch_bounds__(256)
void softmax_bf16(const float* __restrict__ scores, short* __restrict__ alpha, int L)
{
    const int row  = blockIdx.x*4 + (threadIdx.x >> 6);
    const int lane = threadIdx.x & 63;
    const float* p = scores + (long)row*L + lane*8;
    f32x4 v0 = *(const f32x4*)p;
    f32x4 v1 = *(const f32x4*)(p+4);
    float x[8] = {v0[0],v0[1],v0[2],v0[3],v1[0],v1[1],v1[2],v1[3]};
    float m = x[0];
    #pragma unroll
    for (int j=1;j<8;++j) m = fmaxf(m, x[j]);
    #pragma unroll
    for (int off=32; off; off>>=1) m = fmaxf(m, __shfl_xor(m, off));
    float s = 0.f;
    #pragma unroll
    for (int j=0;j<8;++j){ x[j] = __expf(x[j]-m); s += x[j]; }
    #pragma unroll
    for (int off=32; off; off>>=1) s += __shfl_xor(s, off);
    const float rinv = 1.f / s;
    short8 o;
    #pragma unroll
    for (int j=0;j<8;++j) o[j] = f2bf(x[j]*rinv);
    *(short8*)(alpha + (long)row*L + lane*8) = o;
}

// ---------------- fused exact-gelu + LayerNorm, wave per row (H=768) ------
__global__ __launch_bounds__(256)
void gelu_ln(const float* __restrict__ lin, short* __restrict__ h,
             const float* __restrict__ g, const float* __restrict__ b, int H)
{
    const int row  = blockIdx.x*4 + (threadIdx.x >> 6);
    const int lane = threadIdx.x & 63;
    const float* p = lin + (long)row*H;
    float x[12];
    #pragma unroll
    for (int c=0;c<3;++c){
        f32x4 v = *(const f32x4*)(p + c*256 + lane*4);
        x[c*4+0]=v[0]; x[c*4+1]=v[1]; x[c*4+2]=v[2]; x[c*4+3]=v[3];
    }
    float sum=0.f, sq=0.f;
    #pragma unroll
    for (int j=0;j<12;++j){
        float t = 0.5f * x[j] * (1.f + erff(x[j]*0.70710678118654752f));
        x[j] = t; sum += t; sq += t*t;
    }
    #pragma unroll
    for (int off=32; off; off>>=1){ sum += __shfl_xor(sum, off); sq += __shfl_xor(sq, off); }
    const float mu  = sum * (1.f/768.f);
    const float var = sq  * (1.f/768.f) - mu*mu;
    const float inv = rsqrtf(var + 1e-12f);
    #pragma unroll
    for (int c=0;c<3;++c){
        short4v o;
        #pragma unroll
        for (int j=0;j<4;++j){
            int col = c*256 + lane*4 + j;
            o[j] = f2bf((x[c*4+j]-mu)*inv*g[col] + b[col]);
        }
        *(short4v*)(h + (long)row*H + c*256 + lane*4) = o;
    }
}

// --------------------------------------------------------------------------
extern "C" void kernel_launch(void* const* d_in, const int* in_sizes, int n_in,
                              void* d_out, int out_size, void* d_ws, size_t ws_size,
                              hipStream_t stream)
{
    const float* src_scores = (const float*)d_in[0];
    const float* seq_hidden = (const float*)d_in[1];
    const float* seq_mask   = (const float*)d_in[2];
    const float* pos_emb    = (const float*)d_in[3];
    const float* Wp         = (const float*)d_in[4];
    const float* bp         = (const float*)d_in[5];
    const float* Wt         = (const float*)d_in[6];
    const float* bt         = (const float*)d_in[7];
    const float* ln_g       = (const float*)d_in[8];
    const float* ln_b       = (const float*)d_in[9];
    const float* Wd         = (const float*)d_in[10];
    const float* dec_bias   = (const float*)d_in[11];
    float* out = (float*)d_out;

    const int B=8, L=512, H=768, V=30522, Vp=30592, Kp=256;

    // ws: only stage-6 inputs must survive until the final GEMM (53.3 MB)
    const size_t need = ((size_t)Vp*H + (size_t)B*L*H) * sizeof(short);
    if (ws_size < need) return;
    short* wd_bf = (short*)d_ws;               // [Vp, H] bf16, zero-padded rows
    short* h_bf  = wd_bf + (long)Vp*H;         // [B*L, H] bf16

    // everything else is dead before stage 6 -> stash in d_out (500 MB)
    char* sc = (char*)d_out;
    short* sh_nat = (short*)sc;  sc += (long)B*L*H*2;   // [b][s][h] bf16
    short* sh_t   = (short*)sc;  sc += (long)B*L*H*2;   // [b][h][s] bf16
    short* pe_p   = (short*)sc;  sc += (long)L*Kp*2;    // [512,256] bf16 (K-pad)
    short* wp_p   = (short*)sc;  sc += (long)H*Kp*2;    // [768,256] bf16
    short* pos_h  = (short*)sc;  sc += (long)L*H*2;     // [512,768] bf16
    short* wt_bf  = (short*)sc;  sc += (long)H*H*2;     // [768,768] bf16
    float* scoresb= (float*)sc;  sc += (long)B*L*L*4;   // [8,512,512] f32
    short* alpha  = (short*)sc;  sc += (long)B*L*L*2;   // [8,512,512] bf16
    short* seqsum = (short*)sc;  sc += (long)B*L*H*2;   // [8,512,768] bf16
    float* lin5   = (float*)sc;  sc += (long)B*L*H*4;   // [4096,768] f32

    // --- conversions ---
    {   long n=(long)V*H, ntot=(long)Vp*H;
        int blocks=(int)((ntot+2047)/2048); if (blocks>2048) blocks=2048;
        conv_bf16<<<dim3(blocks),256,0,stream>>>(Wd, wd_bf, n, ntot); }
    {   long n=(long)H*H; int blocks=(int)((n+2047)/2048);
        conv_bf16<<<dim3(blocks),256,0,stream>>>(Wt, wt_bf, n, n); }
    {   long n=(long)B*L*H; int blocks=(int)((n+2047)/2048); if (blocks>2048) blocks=2048;
        conv_bf16<<<dim3(blocks),256,0,stream>>>(seq_hidden, sh_nat, n, n); }
    transpose_to_bf16<<<dim3(H/32, L/32, B),256,0,stream>>>(seq_hidden, sh_t, L, H);
    {   int total=L*Kp;
        conv_pad<<<dim3((total+255)/256),256,0,stream>>>(pos_emb, pe_p, 200, Kp, total); }
    {   int total=H*Kp;
        conv_pad<<<dim3((total+255)/256),256,0,stream>>>(Wp, wp_p, 200, Kp, total); }

    // --- stage1: pos_h = pos_emb @ Wp^T + bp  -> bf16 [512,768]
    gemm_bt<4,false><<<dim3(H/128, L/128, 1),256,0,stream>>>(
        pe_p, wp_p, nullptr, pos_h, bp, nullptr, nullptr,
        Kp, H, H, 0L, 0L, 0L, 0L, 0);

    // --- stage2: scores[b,l,s] = pos_h[l].sh[b,s] + src + mask*-1e4 (f32)
    gemm_bt<0,false><<<dim3(L/128, L/128, B),256,0,stream>>>(
        pos_h, sh_nat, scoresb, nullptr, nullptr, src_scores, seq_mask,
        H, L, L, 0L, (long)L*H, (long)L*L, (long)L*L, L);

    // --- stage3: softmax rows of 512 -> alpha bf16
    softmax_bf16<<<dim3(B*L/4),256,0,stream>>>(scoresb, alpha, L);

    // --- stage4: seqsum[b,l,h] = alpha[b,l,:] @ sh[b,:,h]  (B^T = sh_t)
    gemm_bt<1,false><<<dim3(H/128, L/128, B),256,0,stream>>>(
        alpha, sh_t, nullptr, seqsum, nullptr, nullptr, nullptr,
        L, H, H, (long)L*L, (long)H*L, (long)L*H, 0L, 0);

    // --- stage5: lin5 = seqsum @ Wt^T + bt (f32)
    gemm_bt<3,false><<<dim3(H/128, (B*L)/128, 1),256,0,stream>>>(
        seqsum, wt_bf, lin5, nullptr, bt, nullptr, nullptr,
        H, H, H, 0L, 0L, 0L, 0L, 0);

    // --- gelu(exact) + LayerNorm -> h bf16
    gelu_ln<<<dim3(B*L/4),256,0,stream>>>(lin5, h_bf, ln_g, ln_b, H);

    // --- stage6: out = h @ Wd^T + dec_bias  [4096, 30522] f32.
    //     256^2 8-wave dbuf kernel; grid 120 N-panels x 16 M-panels (covers
    //     30720 B-rows; staging rows clamped to Vp-1, stores col-guarded).
    //     T2D supertiling keeps an 8-panel Wd band L2-hot.
    gemm_bt256<true><<<dim3(120, 16), 512, 0, stream>>>(
        h_bf, wd_bf, out, dec_bias, H, V, V, Vp - 1);
}

// Round 8
// 481.768 us; speedup vs baseline: 1.1572x; 1.1572x over previous
//
#include <hip/hip_runtime.h>

using f32x4  = __attribute__((ext_vector_type(4))) float;
using short8 = __attribute__((ext_vector_type(8))) short;
using short4v= __attribute__((ext_vector_type(4))) short;
typedef __attribute__((ext_vector_type(8))) __bf16 bf16x8;

__device__ static inline short f2bf(float f){
    unsigned u = __builtin_bit_cast(unsigned, f);
    u += 0x7fffu + ((u >> 16) & 1u);      // RNE
    return (short)(u >> 16);
}

__device__ static inline void gload_lds16(const void* g, void* l){
    __builtin_amdgcn_global_load_lds(
        (const __attribute__((address_space(1))) void*)g,
        (__attribute__((address_space(3))) void*)l, 16, 0, 0);
}

#define BARM() asm volatile("s_barrier" ::: "memory")

// ---------------- GEMM: C[M,N] = A[M,K] @ B[N,K]^T  (bf16 in, f32 acc) ----
// 128x128 tile, BK=64, 4 waves of 64x64 — proven m97-style kernel, used for
// the small/medium stages. (Stage 6 uses gemm_bt256p below.)
#define BKK 64

template<int EPI, bool T2D>
__global__ __launch_bounds__(256, 2)
void gemm_bt(const short* __restrict__ A, const short* __restrict__ B,
             float* __restrict__ outF, short* __restrict__ outB,
             const float* __restrict__ bias,
             const float* __restrict__ addmat, const float* __restrict__ mask,
             int K, int ldc, int Ncheck,
             long sA, long sB, long sC, long sX, int maskStride)
{
    __shared__ short Abuf[128*BKK];
    __shared__ short Bbuf[128*BKK];
    const int tid  = threadIdx.x;
    const int wave = tid >> 6;
    const int lane = tid & 63;
    const int bz   = blockIdx.z;

    int bx = blockIdx.x, by = blockIdx.y;
    if constexpr (T2D) {
        const int GX = gridDim.x, GY = gridDim.y;
        const int f  = blockIdx.y * GX + blockIdx.x;
        const int nfull  = GX >> 3;
        const int fullsz = (nfull << 3) * GY;
        int mg, mloc, nloc, nbase;
        if (f < fullsz) {
            const int band = f / (GY << 3);
            const int r    = f - band * (GY << 3);
            mg   = r >> 6;
            const int rr = r & 63;
            mloc = rr & 7; nloc = rr >> 3;
            nbase = band << 3;
        } else {
            const int rem = GX & 7;
            const int fp  = f - fullsz;
            const int gsz = rem << 3;
            mg   = fp / gsz;
            const int rr = fp - mg * gsz;
            mloc = rr & 7; nloc = rr >> 3;
            nbase = nfull << 3;
        }
        bx = nbase + nloc;
        by = (mg << 3) + mloc;
    }
    const int m0 = by * 128;
    const int n0 = bx * 128;
    const short* Ab = A + (long)bz * sA;
    const short* Bb = B + (long)bz * sB;

    const int wr = (wave >> 1) * 64;
    const int wc = (wave &  1) * 64;

    f32x4 acc[4][4];
    #pragma unroll
    for (int i=0;i<4;++i)
        #pragma unroll
        for (int j=0;j<4;++j) acc[i][j] = (f32x4){0.f,0.f,0.f,0.f};

    const int srow = wave*32 + (lane >> 3);
    const int kch  = (lane & 7) ^ (lane >> 3);
    const short* gA = Ab + (long)(m0 + srow)*K + kch*8;
    const short* gB = Bb + (long)(n0 + srow)*K + kch*8;
    short* lA = Abuf + wave*32*BKK;
    short* lB = Bbuf + wave*32*BKK;

    for (int k0 = 0; k0 < K; k0 += BKK) {
        __syncthreads();
        #pragma unroll
        for (int is=0; is<4; ++is){
            gload_lds16(gA + k0 + (long)is*8*K, lA + is*8*BKK);
            gload_lds16(gB + k0 + (long)is*8*K, lB + is*8*BKK);
        }
        __syncthreads();
        #pragma unroll
        for (int ks=0; ks<2; ++ks){
            bf16x8 af[4], bfr[4];
            const int chunk = ks*4 + (lane >> 4);
            #pragma unroll
            for (int mi=0;mi<4;++mi){
                int row = wr + mi*16 + (lane & 15);
                af[mi] = *(const bf16x8*)((const char*)Abuf + row*128 + ((chunk ^ (row & 7))<<4));
            }
            #pragma unroll
            for (int ni=0;ni<4;++ni){
                int row = wc + ni*16 + (lane & 15);
                bfr[ni] = *(const bf16x8*)((const char*)Bbuf + row*128 + ((chunk ^ (row & 7))<<4));
            }
            #pragma unroll
            for (int mi=0;mi<4;++mi)
                #pragma unroll
                for (int ni=0;ni<4;++ni)
                    acc[mi][ni] = __builtin_amdgcn_mfma_f32_16x16x32_bf16(af[mi], bfr[ni], acc[mi][ni], 0, 0, 0);
        }
    }

    const int rb = (lane >> 4) * 4;
    const int cb = lane & 15;
    #pragma unroll
    for (int mi=0;mi<4;++mi){
        #pragma unroll
        for (int r=0;r<4;++r){
            const int row = m0 + wr + mi*16 + rb + r;
            #pragma unroll
            for (int ni=0;ni<4;++ni){
                const int col = n0 + wc + ni*16 + cb;
                float v = acc[mi][ni][r];
                if constexpr (EPI == 0) {
                    v += addmat[(long)bz*sX + (long)row*ldc + col]
                         - 10000.f * mask[bz*maskStride + col];
                    outF[(long)bz*sC + (long)row*ldc + col] = v;
                } else if constexpr (EPI == 1) {
                    outB[(long)bz*sC + (long)row*ldc + col] = f2bf(v);
                } else if constexpr (EPI == 3) {
                    if (col < Ncheck) outF[(long)row*ldc + col] = v + bias[col];
                } else if constexpr (EPI == 4) {
                    outB[(long)row*ldc + col] = f2bf(v + bias[col]);
                }
            }
        }
    }
}

// ------- stage-6 GEMM: 256x256, 8 waves, BK=64, 4-phase interleave --------
// 8-phase-template port (m194-m201 mechanism): per K-tile, 4 sub-phases of
// {ds_read subtile | issue 2 staging loads | [vmcnt(4)] | barrier |
//  setprio(1) 16 MFMA setprio(0) | barrier}.
// Staging units per tile: A.ks0, B.ks0, A.ks1, B.ks1 (2 gload_lds each),
// issued one unit per phase into the opposite buffer. vmcnt(4) at odd phases
// -> every unit is waited exactly 4 phases (~1 K-tile of MFMA) after issue;
// never drains in the main loop (T4).
// LDS [buf][kh][256][32] K-half-major planes: each unit = linear 16 KB so
// global_load_lds' wave-uniform-base+lane*16 dest works; address math
// (pre-swizzled source chunk, (lane>>1)&3 read XOR) identical to the R7
// kernel that measured 0 bank conflicts.
template<bool T2D>
__global__ __launch_bounds__(512, 1)
void gemm_bt256p(const short* __restrict__ A, const short* __restrict__ B,
                 float* __restrict__ outF, const float* __restrict__ bias,
                 int K, int ldc, int Ncheck, int maxBrow)
{
    __shared__ __align__(16) short Ab[2][2][256*32];   // 64 KB
    __shared__ __align__(16) short Bb[2][2][256*32];   // 64 KB
    const int tid  = threadIdx.x;
    const int wave = tid >> 6;
    const int lane = tid & 63;

    int bx = blockIdx.x, by = blockIdx.y;
    if constexpr (T2D) {   // 8x8 super-tiles (proven: FETCH 766->209 MB)
        const int GX = gridDim.x, GY = gridDim.y;
        const int f  = blockIdx.y * GX + blockIdx.x;
        const int band = f / (GY << 3);
        const int r2   = f - band * (GY << 3);
        const int mg   = r2 >> 6;
        const int rr   = r2 & 63;
        bx = (band << 3) + (rr >> 3);
        by = (mg << 3) + (rr & 7);
    }
    const int m0 = by * 256;
    const int n0 = bx * 256;

    const int wr = (wave >> 2) * 128;   // wave M offset
    const int wc = (wave & 3) * 64;     // wave N offset

    f32x4 acc[8][4];
    #pragma unroll
    for (int i=0;i<8;++i)
        #pragma unroll
        for (int j=0;j<4;++j) acc[i][j] = (f32x4){0.f,0.f,0.f,0.f};

    // ---- staging addresses (R7-proven math, kh-major planes) ----
    const int srow = wave*16 + (lane >> 2);              // [0,128)
    const int cg   = (lane & 3) ^ ((lane >> 3) & 3);     // pre-swizzled chunk
    const short* gA0 = A + (long)(m0 + srow)       * K + cg*8;
    const short* gA1 = gA0 + (long)128 * K;
    int br0 = n0 + srow;        if (br0 > maxBrow) br0 = maxBrow;
    int br1 = n0 + 128 + srow;  if (br1 > maxBrow) br1 = maxBrow;
    const short* gB0 = B + (long)br0 * K + cg*8;
    const short* gB1 = B + (long)br1 * K + cg*8;
    const int so = wave*16*32;                           // wave-uniform base

    const int nt = K / 64;

    #define SA(bb,kh,kc) { gload_lds16(gA0 + (kc) + (kh)*32, &Ab[bb][kh][so]); \
                           gload_lds16(gA1 + (kc) + (kh)*32, &Ab[bb][kh][128*32 + so]); }
    #define SB(bb,kh,kc) { gload_lds16(gB0 + (kc) + (kh)*32, &Bb[bb][kh][so]); \
                           gload_lds16(gB1 + (kc) + (kh)*32, &Bb[bb][kh][128*32 + so]); }

    // ---- ds_read addresses (R7-proven, 0 conflicts) ----
    const int ch   = (lane >> 4) ^ ((lane >> 1) & 3);
    const int aoff = (wr + (lane & 15))*32 + ch*8;
    const int boff = (wc + (lane & 15))*32 + ch*8;

    // prologue: tile 0, units in order A0,B0,A1,B1; wait first two units
    SA(0,0,0); SB(0,0,0); SA(0,1,0); SB(0,1,0);
    asm volatile("s_waitcnt vmcnt(4)" ::: "memory");
    BARM();

    for (int t = 0; t < nt; ++t) {
        const int buf = t & 1, nb = buf ^ 1;
        const bool pf = (t + 1) < nt;
        const long kc = (long)(t + 1) * 64;
        bf16x8 af[8], bq[2];

        #define RDA(kh) { _Pragma("unroll") \
            for (int mi=0;mi<8;++mi) af[mi] = *(const bf16x8*)&Ab[buf][kh][aoff + mi*512]; }
        #define RDB(kh,n0i) { bq[0] = *(const bf16x8*)&Bb[buf][kh][boff + (n0i)*512]; \
                              bq[1] = *(const bf16x8*)&Bb[buf][kh][boff + (n0i+1)*512]; }
        #define MF(n0i) { __builtin_amdgcn_s_setprio(1); _Pragma("unroll") \
            for (int mi=0;mi<8;++mi){ \
                acc[mi][n0i]   = __builtin_amdgcn_mfma_f32_16x16x32_bf16(af[mi], bq[0], acc[mi][n0i],   0,0,0); \
                acc[mi][n0i+1] = __builtin_amdgcn_mfma_f32_16x16x32_bf16(af[mi], bq[1], acc[mi][n0i+1], 0,0,0); } \
            __builtin_amdgcn_s_setprio(0); }

        // ---- phase 0: ks0, N cols 0-1 ----
        RDA(0); RDB(0,0);
        if (pf) SA(nb,0,kc);
        BARM();
        MF(0);
        BARM();
        // ---- phase 1: ks0, N cols 2-3 ----
        RDB(0,2);
        if (pf) { SB(nb,0,kc); asm volatile("s_waitcnt vmcnt(4)" ::: "memory"); }
        else    {              asm volatile("s_waitcnt vmcnt(0)" ::: "memory"); }
        BARM();
        MF(2);
        BARM();
        // ---- phase 2: ks1, N cols 0-1 ----
        RDA(1); RDB(1,0);
        if (pf) SA(nb,1,kc);
        BARM();
        MF(0);
        BARM();
        // ---- phase 3: ks1, N cols 2-3 ----
        RDB(1,2);
        if (pf) { SB(nb,1,kc); asm volatile("s_waitcnt vmcnt(4)" ::: "memory"); }
        else    {              asm volatile("s_waitcnt vmcnt(0)" ::: "memory"); }
        BARM();
        MF(2);
        BARM();

        #undef RDA
        #undef RDB
        #undef MF
    }

    // epilogue (R7-proven layout): col=lane&15, row=(lane>>4)*4+reg
    const int rb = (lane >> 4) * 4;
    const int cb = lane & 15;
    #pragma unroll
    for (int mi=0;mi<8;++mi){
        #pragma unroll
        for (int r=0;r<4;++r){
            const long row = (long)m0 + wr + mi*16 + rb + r;
            #pragma unroll
            for (int ni=0;ni<4;++ni){
                const int col = n0 + wc + ni*16 + cb;
                if (col < Ncheck)
                    outF[row*ldc + col] = acc[mi][ni][r] + bias[col];
            }
        }
    }
}

// ---------------- f32 -> bf16 (vector, zero-pad tail [n, ntot)) -----------
__global__ __launch_bounds__(256)
void conv_bf16(const float* __restrict__ in, short* __restrict__ out, long n, long ntot)
{
    const long stride = (long)gridDim.x * 2048;
    for (long i = ((long)blockIdx.x*256 + threadIdx.x)*8; i < ntot; i += stride){
        short8 o = (short8){0,0,0,0,0,0,0,0};
        if (i < n){
            f32x4 a = *(const f32x4*)(in + i);
            f32x4 b = *(const f32x4*)(in + i + 4);
            o[0]=f2bf(a[0]); o[1]=f2bf(a[1]); o[2]=f2bf(a[2]); o[3]=f2bf(a[3]);
            o[4]=f2bf(b[0]); o[5]=f2bf(b[1]); o[6]=f2bf(b[2]); o[7]=f2bf(b[3]);
        }
        *(short8*)(out + i) = o;
    }
}

// ---------------- f32 [R,Cin] -> bf16 [R,Cpad], zero cols >= Cin ----------
__global__ __launch_bounds__(256)
void conv_pad(const float* __restrict__ in, short* __restrict__ out,
              int Cin, int Cpad, int total)
{
    int idx = blockIdx.x*256 + threadIdx.x;
    if (idx >= total) return;
    int r = idx / Cpad, c = idx - r*Cpad;
    short v = 0;
    if (c < Cin) v = f2bf(in[(long)r*Cin + c]);
    out[idx] = v;
}

// ---------------- per-batch transpose f32 [R,C] -> bf16 [C,R] -------------
__global__ __launch_bounds__(256)
void transpose_to_bf16(const float* __restrict__ in, short* __restrict__ out, int R, int C)
{
    __shared__ float t[32][33];
    const long boff = (long)blockIdx.z * R * C;
    const float* inb = in + boff;
    short* outb = out + boff;
    int c0 = blockIdx.x*32, r0 = blockIdx.y*32;
    int tx = threadIdx.x & 31, ty = threadIdx.x >> 5;   // 32 x 8
    #pragma unroll
    for (int j=0;j<32;j+=8) t[ty+j][tx] = inb[(long)(r0+ty+j)*C + c0+tx];
    __syncthreads();
    #pragma unroll
    for (int j=0;j<32;j+=8) outb[(long)(c0+ty+j)*R + r0+tx] = f2bf(t[tx][ty+j]);
}

// ---------------- wave-per-row softmax, f32 [.,512] -> bf16 ---------------
__global__ __launch_bounds__(256)
void softmax_bf16(const float* __restrict__ scores, short* __restrict__ alpha, int L)
{
    const int row  = blockIdx.x*4 + (threadIdx.x >> 6);
    const int lane = threadIdx.x & 63;
    const float* p = scores + (long)row*L + lane*8;
    f32x4 v0 = *(const f32x4*)p;
    f32x4 v1 = *(const f32x4*)(p+4);
    float x[8] = {v0[0],v0[1],v0[2],v0[3],v1[0],v1[1],v1[2],v1[3]};
    float m = x[0];
    #pragma unroll
    for (int j=1;j<8;++j) m = fmaxf(m, x[j]);
    #pragma unroll
    for (int off=32; off; off>>=1) m = fmaxf(m, __shfl_xor(m, off));
    float s = 0.f;
    #pragma unroll
    for (int j=0;j<8;++j){ x[j] = __expf(x[j]-m); s += x[j]; }
    #pragma unroll
    for (int off=32; off; off>>=1) s += __shfl_xor(s, off);
    const float rinv = 1.f / s;
    short8 o;
    #pragma unroll
    for (int j=0;j<8;++j) o[j] = f2bf(x[j]*rinv);
    *(short8*)(alpha + (long)row*L + lane*8) = o;
}

// ---------------- fused exact-gelu + LayerNorm, wave per row (H=768) ------
__global__ __launch_bounds__(256)
void gelu_ln(const float* __restrict__ lin, short* __restrict__ h,
             const float* __restrict__ g, const float* __restrict__ b, int H)
{
    const int row  = blockIdx.x*4 + (threadIdx.x >> 6);
    const int lane = threadIdx.x & 63;
    const float* p = lin + (long)row*H;
    float x[12];
    #pragma unroll
    for (int c=0;c<3;++c){
        f32x4 v = *(const f32x4*)(p + c*256 + lane*4);
        x[c*4+0]=v[0]; x[c*4+1]=v[1]; x[c*4+2]=v[2]; x[c*4+3]=v[3];
    }
    float sum=0.f, sq=0.f;
    #pragma unroll
    for (int j=0;j<12;++j){
        float t = 0.5f * x[j] * (1.f + erff(x[j]*0.70710678118654752f));
        x[j] = t; sum += t; sq += t*t;
    }
    #pragma unroll
    for (int off=32; off; off>>=1){ sum += __shfl_xor(sum, off); sq += __shfl_xor(sq, off); }
    const float mu  = sum * (1.f/768.f);
    const float var = sq  * (1.f/768.f) - mu*mu;
    const float inv = rsqrtf(var + 1e-12f);
    #pragma unroll
    for (int c=0;c<3;++c){
        short4v o;
        #pragma unroll
        for (int j=0;j<4;++j){
            int col = c*256 + lane*4 + j;
            o[j] = f2bf((x[c*4+j]-mu)*inv*g[col] + b[col]);
        }
        *(short4v*)(h + (long)row*H + c*256 + lane*4) = o;
    }
}

// --------------------------------------------------------------------------
extern "C" void kernel_launch(void* const* d_in, const int* in_sizes, int n_in,
                              void* d_out, int out_size, void* d_ws, size_t ws_size,
                              hipStream_t stream)
{
    const float* src_scores = (const float*)d_in[0];
    const float* seq_hidden = (const float*)d_in[1];
    const float* seq_mask   = (const float*)d_in[2];
    const float* pos_emb    = (const float*)d_in[3];
    const float* Wp         = (const float*)d_in[4];
    const float* bp         = (const float*)d_in[5];
    const float* Wt         = (const float*)d_in[6];
    const float* bt         = (const float*)d_in[7];
    const float* ln_g       = (const float*)d_in[8];
    const float* ln_b       = (const float*)d_in[9];
    const float* Wd         = (const float*)d_in[10];
    const float* dec_bias   = (const float*)d_in[11];
    float* out = (float*)d_out;

    const int B=8, L=512, H=768, V=30522, Vp=30592, Kp=256;

    // ws: only stage-6 inputs must survive until the final GEMM (53.3 MB)
    const size_t need = ((size_t)Vp*H + (size_t)B*L*H) * sizeof(short);
    if (ws_size < need) return;
    short* wd_bf = (short*)d_ws;               // [Vp, H] bf16, zero-padded rows
    short* h_bf  = wd_bf + (long)Vp*H;         // [B*L, H] bf16

    // everything else is dead before stage 6 -> stash in d_out (500 MB)
    char* sc = (char*)d_out;
    short* sh_nat = (short*)sc;  sc += (long)B*L*H*2;   // [b][s][h] bf16
    short* sh_t   = (short*)sc;  sc += (long)B*L*H*2;   // [b][h][s] bf16
    short* pe_p   = (short*)sc;  sc += (long)L*Kp*2;    // [512,256] bf16 (K-pad)
    short* wp_p   = (short*)sc;  sc += (long)H*Kp*2;    // [768,256] bf16
    short* pos_h  = (short*)sc;  sc += (long)L*H*2;     // [512,768] bf16
    short* wt_bf  = (short*)sc;  sc += (long)H*H*2;     // [768,768] bf16
    float* scoresb= (float*)sc;  sc += (long)B*L*L*4;   // [8,512,512] f32
    short* alpha  = (short*)sc;  sc += (long)B*L*L*2;   // [8,512,512] bf16
    short* seqsum = (short*)sc;  sc += (long)B*L*H*2;   // [8,512,768] bf16
    float* lin5   = (float*)sc;  sc += (long)B*L*H*4;   // [4096,768] f32

    // --- conversions ---
    {   long n=(long)V*H, ntot=(long)Vp*H;
        int blocks=(int)((ntot+2047)/2048); if (blocks>2048) blocks=2048;
        conv_bf16<<<dim3(blocks),256,0,stream>>>(Wd, wd_bf, n, ntot); }
    {   long n=(long)H*H; int blocks=(int)((n+2047)/2048);
        conv_bf16<<<dim3(blocks),256,0,stream>>>(Wt, wt_bf, n, n); }
    {   long n=(long)B*L*H; int blocks=(int)((n+2047)/2048); if (blocks>2048) blocks=2048;
        conv_bf16<<<dim3(blocks),256,0,stream>>>(seq_hidden, sh_nat, n, n); }
    transpose_to_bf16<<<dim3(H/32, L/32, B),256,0,stream>>>(seq_hidden, sh_t, L, H);
    {   int total=L*Kp;
        conv_pad<<<dim3((total+255)/256),256,0,stream>>>(pos_emb, pe_p, 200, Kp, total); }
    {   int total=H*Kp;
        conv_pad<<<dim3((total+255)/256),256,0,stream>>>(Wp, wp_p, 200, Kp, total); }

    // --- stage1: pos_h = pos_emb @ Wp^T + bp  -> bf16 [512,768]
    gemm_bt<4,false><<<dim3(H/128, L/128, 1),256,0,stream>>>(
        pe_p, wp_p, nullptr, pos_h, bp, nullptr, nullptr,
        Kp, H, H, 0L, 0L, 0L, 0L, 0);

    // --- stage2: scores[b,l,s] = pos_h[l].sh[b,s] + src + mask*-1e4 (f32)
    gemm_bt<0,false><<<dim3(L/128, L/128, B),256,0,stream>>>(
        pos_h, sh_nat, scoresb, nullptr, nullptr, src_scores, seq_mask,
        H, L, L, 0L, (long)L*H, (long)L*L, (long)L*L, L);

    // --- stage3: softmax rows of 512 -> alpha bf16
    softmax_bf16<<<dim3(B*L/4),256,0,stream>>>(scoresb, alpha, L);

    // --- stage4: seqsum[b,l,h] = alpha[b,l,:] @ sh[b,:,h]  (B^T = sh_t)
    gemm_bt<1,false><<<dim3(H/128, L/128, B),256,0,stream>>>(
        alpha, sh_t, nullptr, seqsum, nullptr, nullptr, nullptr,
        L, H, H, (long)L*L, (long)H*L, (long)L*H, 0L, 0);

    // --- stage5: lin5 = seqsum @ Wt^T + bt (f32)
    gemm_bt<3,false><<<dim3(H/128, (B*L)/128, 1),256,0,stream>>>(
        seqsum, wt_bf, lin5, nullptr, bt, nullptr, nullptr,
        H, H, H, 0L, 0L, 0L, 0L, 0);

    // --- gelu(exact) + LayerNorm -> h bf16
    gelu_ln<<<dim3(B*L/4),256,0,stream>>>(lin5, h_bf, ln_g, ln_b, H);

    // --- stage6: out = h @ Wd^T + dec_bias  [4096, 30522] f32.
    //     256^2 / BK=64 / 4-phase interleaved kernel (counted vmcnt(4),
    //     setprio, phase barriers) + T2D supertiling.
    gemm_bt256p<true><<<dim3(120, 16), 512, 0, stream>>>(
        h_bf, wd_bf, out, dec_bias, H, V, V, Vp - 1);
}